// Round 12
// baseline (1602.741 us; speedup 1.0000x reference)
//
#include <hip/hip_runtime.h>
#include <stdint.h>
#include <math.h>

typedef float fx4 __attribute__((ext_vector_type(4)));
typedef float fx16 __attribute__((ext_vector_type(16)));
typedef int   ix4 __attribute__((ext_vector_type(4)));
typedef int   ix8 __attribute__((ext_vector_type(8)));

#define NB 4096
#define ND 1024
#define CEPS 1e-6f
#define CTHR 0.5f
#define NT8 8            // K-tiles of 128: 1024/128

// ---------- helpers ----------

__device__ __forceinline__ void gload16(const void* g, void* l) {
  __builtin_amdgcn_global_load_lds(
      (const __attribute__((address_space(1))) uint32_t*)(uintptr_t)g,
      (__attribute__((address_space(3))) uint32_t*)(uint32_t)(uintptr_t)l,
      16, 0, 0);
}

__device__ __forceinline__ ix8 ldfrag8(const char* p0, const char* p1) {
  const ix4 lo = *(const ix4*)p0;
  const ix4 hi = *(const ix4*)p1;
  ix8 r;
  r[0] = lo[0]; r[1] = lo[1]; r[2] = lo[2]; r[3] = lo[3];
  r[4] = hi[0]; r[5] = hi[1]; r[6] = hi[2]; r[7] = hi[3];
  return r;
}

// fp8 e4m3 (OCP on gfx950), scales = 127 (x1.0) — validated R4/R7/R8/R9/R10
#define MFMAS(A, B, C) \
  __builtin_amdgcn_mfma_scale_f32_32x32x64_f8f6f4((A), (B), (C), 0, 0, 0, 127, 0, 127)

// ---------- kernel 1: f32 -> fp8 convert + row norms (f32) ----------

__global__ __launch_bounds__(256) void cmc_convert(
    const float* __restrict__ in, uint8_t* __restrict__ xf8,
    float* __restrict__ lnorm) {
  const int row = blockIdx.x;           // 0 .. 3*4096-1
  const int tid = threadIdx.x;
  const fx4 v = *(const fx4*)(in + (size_t)row * ND + tid * 4);
  int pk = __builtin_amdgcn_cvt_pk_fp8_f32(v[0], v[1], 0, false);
  pk = __builtin_amdgcn_cvt_pk_fp8_f32(v[2], v[3], pk, true);
  ((int*)(xf8 + (size_t)row * ND))[tid] = pk;
  float ss = v[0]*v[0] + v[1]*v[1] + v[2]*v[2] + v[3]*v[3];
  #pragma unroll
  for (int d = 1; d < 64; d <<= 1) ss += __shfl_xor(ss, d);
  __shared__ float sred[4];
  if ((tid & 63) == 0) sred[tid >> 6] = ss;
  __syncthreads();
  if (tid == 0) lnorm[row] = sqrtf(sred[0] + sred[1] + sred[2] + sred[3]);
}

// ---------- 128x256 fp8 gram, BK=128, 8 waves (64x64 each), single-buffer ----------
// LDS 48 KiB: A [128 rows][128 B] @0, B [256 rows][128 B] @16384.
// Swizzle: stored_byte(r,c) = r*128 + (c ^ ((r&7)<<4)); staging source col
// pre-swizzled (rule #21), global_load_lds dest linear.
// R7/R10 mechanism (multi-block TLP hides drains, 3 blocks/CU) with 2x MFMA
// per drain: 64 MFMA per block-ktile for the same 2 barriers.

__device__ __forceinline__ void gram128x256(
    const uint8_t* __restrict__ Xi, const uint8_t* __restrict__ Xj,
    int rb, int cb, char* smem, int tid, fx16 (&acc)[2][2]) {
  const int l = tid & 63, w = tid >> 6;
  const int wr = w >> 2, wc = w & 3;     // wave grid 2 x 4, wave tile 64x64
  // staging: pass s covers stored bytes s*8192 + tid*16; row = s*64 + (tid>>3)
  const int scol = (((tid & 7) ^ ((tid >> 3) & 7)) << 4);  // pre-swizzled src col
  const uint8_t* gA = Xi + (size_t)(rb + (tid >> 3)) * ND + scol;
  const uint8_t* gB = Xj + (size_t)(cb + (tid >> 3)) * ND + scol;
  char* dA = smem + tid * 16;
  char* dB = smem + 16384 + tid * 16;

  // frag reads: row = base + (l&31); (row&7) == (l&7)
  const int swz = (l & 7) << 4;
  const int kb = (l >> 5) * 32;          // K sub-block
  const char* rdA = smem + (wr * 64 + (l & 31)) * 128;
  const char* rdB = smem + 16384 + (wc * 64 + (l & 31)) * 128;

  #pragma unroll
  for (int m = 0; m < 2; ++m)
    #pragma unroll
    for (int n = 0; n < 2; ++n)
      #pragma unroll
      for (int e = 0; e < 16; ++e) acc[m][n][e] = 0.f;

  #pragma unroll 1
  for (int t = 0; t < NT8; ++t) {
    const int k0 = t * 128;
    #pragma unroll
    for (int s = 0; s < 2; ++s)          // A: 16 KiB in 2 passes
      gload16(gA + (size_t)s * 64 * ND + k0, dA + s * 8192);
    #pragma unroll
    for (int s = 0; s < 4; ++s)          // B: 32 KiB in 4 passes
      gload16(gB + (size_t)s * 64 * ND + k0, dB + s * 8192);
    __syncthreads();                     // drain: tile landed
    #pragma unroll
    for (int ks = 0; ks < 2; ++ks) {
      const int c0 = (ks * 64 + kb) ^ swz;
      const int c1 = (ks * 64 + kb + 16) ^ swz;
      ix8 A[2], B[2];
      A[0] = ldfrag8(rdA + c0,        rdA + c1);
      A[1] = ldfrag8(rdA + 4096 + c0, rdA + 4096 + c1);
      B[0] = ldfrag8(rdB + c0,        rdB + c1);
      B[1] = ldfrag8(rdB + 4096 + c0, rdB + 4096 + c1);
      acc[0][0] = MFMAS(A[0], B[0], acc[0][0]);
      acc[0][1] = MFMAS(A[0], B[1], acc[0][1]);
      acc[1][0] = MFMAS(A[1], B[0], acc[1][0]);
      acc[1][1] = MFMAS(A[1], B[1], acc[1][1]);
    }
    __syncthreads();                     // all reads consumed before restage
  }
}

// ---------- kernel 2: per-modal self-gram -> bitmask (tile-skip + transpose) ----------
// 128x256 tiles; skip tiles entirely below the diagonal (rb >= cb+256); write
// direct always and transpose always (duplicates carry identical values —
// s1 is symmetric). Coverage audit in R11 notes.

__global__ __launch_bounds__(512, 6) void cmc_selfmask(
    const uint8_t* __restrict__ xf8, const float* __restrict__ lnorm,
    uint32_t* __restrict__ maskw) {
  __shared__ __align__(16) char smem[49152];
  const int md = blockIdx.z;
  const int bx = blockIdx.x, by = blockIdx.y;
  const int rb = by * 128, cb = bx * 256;
  if (rb >= cb + 256) return;            // fully below diagonal: mirrored tile covers
  const int tid = threadIdx.x;
  const int l = tid & 63, w = tid >> 6;
  const int wr = w >> 2, wc = w & 3;

  const uint8_t* X = xf8 + (size_t)md * NB * ND;
  fx16 acc[2][2];
  gram128x256(X, X, rb, cb, smem, tid, acc);

  // threshold -> 128x256 bit tile in LDS (smem free after gram's final sync)
  uint32_t* tile = (uint32_t*)smem;      // [128][8] words = 4 KiB
  float* Lr = (float*)(smem + 4096);     // 128 f
  float* Lc = (float*)(smem + 4608);     // 256 f
  if (tid < 128) Lr[tid] = lnorm[md * NB + rb + tid];
  if (tid < 256) Lc[tid] = lnorm[md * NB + cb + tid];
  __syncthreads();

  #pragma unroll
  for (int m = 0; m < 2; ++m)
    #pragma unroll
    for (int r = 0; r < 16; ++r) {
      const int rl0 = wr * 64 + m * 32 + (r & 3) + 8 * (r >> 2);  // + 4*(l>>5)
      const float Lrv = Lr[rl0 + 4 * (l >> 5)];
      #pragma unroll
      for (int n = 0; n < 2; ++n) {
        const int cl = wc * 64 + n * 32 + (l & 31);
        const float cv = acc[m][n][r] / fmaxf(Lrv * Lc[cl], CEPS);
        const uint64_t b = __ballot(cv <= CTHR);
        if (l == 0)  tile[(rl0 + 0) * 8 + wc * 2 + n] = (uint32_t)b;
        if (l == 32) tile[(rl0 + 4) * 8 + wc * 2 + n] = (uint32_t)(b >> 32);
      }
    }
  __syncthreads();

  // direct region: rows [rb,+128) x words [cb/32,+8) — exclusively owned
  for (int t = tid; t < 1024; t += 512) {
    const int row = t >> 3, wd = t & 7;
    maskw[((size_t)md * NB + rb + row) * 128 + (cb >> 5) + wd] = tile[t];
  }
  // transposed region: rows [cb,+256) x words [rb/32,+4); duplicate-value-safe
  for (int t = tid; t < 1024; t += 512) {
    const int crow = t & 255;
    const int wp = t >> 8;               // 0..3
    uint32_t wv = 0;
    #pragma unroll
    for (int r = 0; r < 32; ++r) {
      const uint32_t bit = (tile[(wp * 32 + r) * 8 + (crow >> 5)] >> (crow & 31)) & 1u;
      wv |= bit << r;
    }
    maskw[((size_t)md * NB + cb + crow) * 128 + (rb >> 5) + wp] = wv;
  }
}

// ---------- kernel 3: per-pair cross gram + masked exp + count row-partials ----------
// Grid 1536 = 8 x 192, XCD-swizzled: each XCD owns a contiguous row-band.

__global__ __launch_bounds__(512, 6) void cmc_pair(
    const uint8_t* __restrict__ xf8, const float* __restrict__ lnorm,
    const uint32_t* __restrict__ maskw,
    float* __restrict__ sumexp, float* __restrict__ cntrow,
    float* __restrict__ diagv) {
  __shared__ __align__(16) char smem[49152];
  const int o = blockIdx.x;              // 0..1535
  const int bid = (o & 7) * 192 + (o >> 3);   // XCD-contiguous (1536 % 8 == 0)
  const int p = bid >> 9;                // 512 tiles per pair
  const int rem = bid & 511;
  const int by = rem >> 4, bx = rem & 15;
  const int mi = (p == 2) ? 1 : 0;
  const int mj = (p == 0) ? 1 : 2;
  const int rb = by * 128, cb = bx * 256;
  const int tid = threadIdx.x;
  const int l = tid & 63, w = tid >> 6;
  const int wr = w >> 2, wc = w & 3;

  const uint8_t* Xi = xf8 + (size_t)mi * NB * ND;
  const uint8_t* Xj = xf8 + (size_t)mj * NB * ND;

  fx16 acc[2][2];
  gram128x256(Xi, Xj, rb, cb, smem, tid, acc);

  // stage masks + norms into LDS (smem free after gram's final sync)
  uint32_t* Mt = (uint32_t*)smem;        // Mi [128][8] then Mj [128][8] = 8 KiB
  float* Lri = (float*)(smem + 8192);    // 128 f
  float* Lcj = (float*)(smem + 8704);    // 256 f
  for (int t = tid; t < 1024; t += 512) {
    const int row = t >> 3, wd = t & 7;
    Mt[t]        = maskw[((size_t)mi * NB + rb + row) * 128 + (cb >> 5) + wd];
    Mt[1024 + t] = maskw[((size_t)mj * NB + rb + row) * 128 + (cb >> 5) + wd];
  }
  if (tid < 128) Lri[tid] = lnorm[mi * NB + rb + tid];
  if (tid < 256) Lcj[tid] = lnorm[mj * NB + cb + tid];
  __syncthreads();

  #pragma unroll
  for (int m = 0; m < 2; ++m)
    #pragma unroll
    for (int r = 0; r < 16; ++r) {
      const int rl = wr * 64 + m * 32 + (r & 3) + 8 * (r >> 2) + 4 * (l >> 5);
      const int rg = rb + rl;
      const float Lrv = Lri[rl];
      float se = 0.f, ct = 0.f;
      #pragma unroll
      for (int n = 0; n < 2; ++n) {
        const int cl = wc * 64 + n * 32 + (l & 31);
        const int cg = cb + cl;
        const uint32_t bi = (Mt[rl * 8 + (cl >> 5)] >> (cl & 31)) & 1u;
        const uint32_t bj = (Mt[1024 + rl * 8 + (cl >> 5)] >> (cl & 31)) & 1u;
        const bool msk = bi | bj | (rg == cg);
        const float logit = acc[m][n][r] / fmaxf(Lrv * Lcj[cl], CEPS) * 10.0f;
        if (rg == cg) diagv[p * NB + rg] = logit;
        if (msk) { se += __expf(logit); ct += 1.f; }
      }
      #pragma unroll
      for (int d = 1; d < 32; d <<= 1) {
        se += __shfl_xor(se, d);
        ct += __shfl_xor(ct, d);
      }
      if ((l & 31) == 0) {
        atomicAdd(&sumexp[p * NB + rg], se);
        atomicAdd(&cntrow[p * NB + rg], ct);
      }
    }
}

// ---------- kernel 4: finalize (1024 threads) ----------

__global__ __launch_bounds__(1024) void cmc_final(
    const float* __restrict__ sumexp, const float* __restrict__ cntrow,
    const float* __restrict__ diagv, float* __restrict__ out) {
  const int tid = threadIdx.x;
  __shared__ float sred[32];
  float lsum = 0.f;
  for (int p = 0; p < 3; ++p) {
    float t = 0.f, c = 0.f;
    for (int r = tid; r < NB; r += 1024) {
      const float cnt = cntrow[p * NB + r];
      if (cnt > 1.0f) {
        t += logf(sumexp[p * NB + r]) - diagv[p * NB + r];
        c += 1.f;
      }
    }
    #pragma unroll
    for (int d = 1; d < 64; d <<= 1) { t += __shfl_xor(t, d); c += __shfl_xor(c, d); }
    if ((tid & 63) == 0) { sred[(tid >> 6) * 2] = t; sred[(tid >> 6) * 2 + 1] = c; }
    __syncthreads();
    if (tid == 0) {
      float tt = 0.f, cc = 0.f;
      #pragma unroll
      for (int q = 0; q < 16; ++q) { tt += sred[2 * q]; cc += sred[2 * q + 1]; }
      lsum += (cc > 0.f) ? tt / fmaxf(cc, 1.f) : 0.f;
    }
    __syncthreads();
  }
  if (tid == 0) out[0] = lsum / 3.0f;
}

// ---------- launch ----------

extern "C" void kernel_launch(void* const* d_in, const int* in_sizes, int n_in,
                              void* d_out, int out_size, void* d_ws, size_t ws_size,
                              hipStream_t stream) {
  const float* in = (const float*)d_in[0];
  float* out = (float*)d_out;
  char* ws = (char*)d_ws;

  const size_t X8_BYTES = (size_t)3 * NB * ND;          // 12,582,912
  uint8_t* xf8  = (uint8_t*)ws;
  float* lnorm  = (float*)(ws + X8_BYTES);
  float* sumexp = lnorm + 3 * NB;
  float* cntrow = sumexp + 3 * NB;
  float* diagv  = cntrow + 3 * NB;
  uint32_t* maskw = (uint32_t*)(diagv + 3 * NB);        // [3][4096][128] = 6 MB

  // zero both atomically-accumulated buffers (sumexp ++ cntrow contiguous)
  hipMemsetAsync(sumexp, 0, (size_t)2 * 3 * NB * sizeof(float), stream);

  cmc_convert<<<3 * NB, 256, 0, stream>>>(in, xf8, lnorm);
  cmc_selfmask<<<dim3(NB / 256, NB / 128, 3), 512, 0, stream>>>(xf8, lnorm, maskw);
  cmc_pair<<<1536, 512, 0, stream>>>(xf8, lnorm, maskw, sumexp, cntrow, diagv);
  cmc_final<<<1, 1024, 0, stream>>>(sumexp, cntrow, diagv, out);
}

// Round 13
// 213.256 us; speedup vs baseline: 7.5156x; 7.5156x over previous
//
#include <hip/hip_runtime.h>
#include <stdint.h>
#include <math.h>

typedef float fx4 __attribute__((ext_vector_type(4)));
typedef float fx16 __attribute__((ext_vector_type(16)));
typedef int   ix4 __attribute__((ext_vector_type(4)));
typedef int   ix8 __attribute__((ext_vector_type(8)));

#define NB 4096
#define ND 1024
#define CEPS 1e-6f
#define CTHR 0.5f
#define NT8 8            // K-tiles of 128: 1024/128

// ---------- helpers ----------

__device__ __forceinline__ void gload16(const void* g, void* l) {
  __builtin_amdgcn_global_load_lds(
      (const __attribute__((address_space(1))) uint32_t*)(uintptr_t)g,
      (__attribute__((address_space(3))) uint32_t*)(uint32_t)(uintptr_t)l,
      16, 0, 0);
}

__device__ __forceinline__ ix8 ldfrag8(const char* p0, const char* p1) {
  const ix4 lo = *(const ix4*)p0;
  const ix4 hi = *(const ix4*)p1;
  ix8 r;
  r[0] = lo[0]; r[1] = lo[1]; r[2] = lo[2]; r[3] = lo[3];
  r[4] = hi[0]; r[5] = hi[1]; r[6] = hi[2]; r[7] = hi[3];
  return r;
}

// fp8 e4m3 (OCP on gfx950), scales = 127 (x1.0) — validated R4/R7-R11
#define MFMAS(A, B, C) \
  __builtin_amdgcn_mfma_scale_f32_32x32x64_f8f6f4((A), (B), (C), 0, 0, 0, 127, 0, 127)

// ---------- kernel 1: f32 -> fp8 convert + row norms (f32) ----------

__global__ __launch_bounds__(256) void cmc_convert(
    const float* __restrict__ in, uint8_t* __restrict__ xf8,
    float* __restrict__ lnorm) {
  const int row = blockIdx.x;           // 0 .. 3*4096-1
  const int tid = threadIdx.x;
  const fx4 v = *(const fx4*)(in + (size_t)row * ND + tid * 4);
  int pk = __builtin_amdgcn_cvt_pk_fp8_f32(v[0], v[1], 0, false);
  pk = __builtin_amdgcn_cvt_pk_fp8_f32(v[2], v[3], pk, true);
  ((int*)(xf8 + (size_t)row * ND))[tid] = pk;
  float ss = v[0]*v[0] + v[1]*v[1] + v[2]*v[2] + v[3]*v[3];
  #pragma unroll
  for (int d = 1; d < 64; d <<= 1) ss += __shfl_xor(ss, d);
  __shared__ float sred[4];
  if ((tid & 63) == 0) sred[tid >> 6] = ss;
  __syncthreads();
  if (tid == 0) lnorm[row] = sqrtf(sred[0] + sred[1] + sred[2] + sred[3]);
}

// ---------- 128x128 fp8 gram, BK=128, 4 waves (64x64), SINGLE-buffer ----------
// R7/R10 structure (proven best: multi-block TLP hides the drain).
// LDS 32 KiB: A [128 rows][128 B] @0, B @16384.
// Swizzle: stored_byte(r,c) = r*128 + (c ^ ((r&7)<<4)); frag reads 4-way
// (the 16B-granularity minimum). Staging source col pre-swizzled (rule #21),
// global_load_lds dest linear. 3 blocks/CU: launch_bounds(256,3), 64 VGPR —
// 3 waves/SIMD x 64 VGPR = 192 <= 512 pool (R11 lesson: check this product).

__device__ __forceinline__ void gram128S(
    const uint8_t* __restrict__ Xi, const uint8_t* __restrict__ Xj,
    int rb, int cb, char* smem, int tid, fx16 (&acc)[2][2]) {
  const int l = tid & 63, w = tid >> 6;
  const int wr = w >> 1, wc = w & 1;     // wave grid 2 x 2, wave tile 64x64
  // staging: pass s covers stored bytes s*4096 + tid*16; row = s*32 + (tid>>3)
  const int srow = tid >> 3;             // 0..31
  const int scol = (((tid & 7) ^ ((tid >> 3) & 7)) << 4);  // pre-swizzled src col
  const uint8_t* gA = Xi + (size_t)(rb + srow) * ND + scol;
  const uint8_t* gB = Xj + (size_t)(cb + srow) * ND + scol;
  char* dA = smem + tid * 16;
  char* dB = smem + 16384 + tid * 16;

  // frag reads: row = base + (l&31); (row&7) == (l&7)
  const int swz = (l & 7) << 4;
  const int kb = (l >> 5) * 32;          // K sub-block
  const char* rdA = smem + (wr * 64 + (l & 31)) * 128;
  const char* rdB = smem + 16384 + (wc * 64 + (l & 31)) * 128;

  #pragma unroll
  for (int m = 0; m < 2; ++m)
    #pragma unroll
    for (int n = 0; n < 2; ++n)
      #pragma unroll
      for (int e = 0; e < 16; ++e) acc[m][n][e] = 0.f;

  #pragma unroll 1
  for (int t = 0; t < NT8; ++t) {
    const int k0 = t * 128;
    #pragma unroll
    for (int s = 0; s < 4; ++s) {
      gload16(gA + (size_t)s * 32 * ND + k0, dA + s * 4096);
      gload16(gB + (size_t)s * 32 * ND + k0, dB + s * 4096);
    }
    __syncthreads();                     // drain: tile landed (vmcnt(0)+barrier)
    #pragma unroll
    for (int ks = 0; ks < 2; ++ks) {
      const int c0 = (ks * 64 + kb) ^ swz;
      const int c1 = (ks * 64 + kb + 16) ^ swz;
      ix8 A[2], B[2];
      A[0] = ldfrag8(rdA + c0,        rdA + c1);
      A[1] = ldfrag8(rdA + 4096 + c0, rdA + 4096 + c1);
      B[0] = ldfrag8(rdB + c0,        rdB + c1);
      B[1] = ldfrag8(rdB + 4096 + c0, rdB + 4096 + c1);
      acc[0][0] = MFMAS(A[0], B[0], acc[0][0]);
      acc[0][1] = MFMAS(A[0], B[1], acc[0][1]);
      acc[1][0] = MFMAS(A[1], B[0], acc[1][0]);
      acc[1][1] = MFMAS(A[1], B[1], acc[1][1]);
    }
    __syncthreads();                     // all reads consumed before restage
  }
}

// ---------- kernel 2: per-modal self-gram -> bitmask (COMPACT upper-tri grid) ----------
// 1D grid 1584 = 3 modals x 528 upper-tri tiles = 8 x 198, XCD-swizzled.
// No dead blocks (R10 launched 3072 with 1488 early-returns).

__global__ __launch_bounds__(256, 3) void cmc_selfmask(
    const uint8_t* __restrict__ xf8, const float* __restrict__ lnorm,
    uint32_t* __restrict__ maskw) {
  __shared__ __align__(16) char smem[32768];
  const int o = blockIdx.x;              // 0..1583
  const int bid = (o & 7) * 198 + (o >> 3);   // XCD-contiguous (1584 % 8 == 0)
  const int md = bid / 528;
  int k = bid - md * 528;                // upper-tri tile index within modal
  int by = 0;
  while (k >= 32 - by) { k -= 32 - by; ++by; }   // uniform scalar decode
  const int bx = by + k;
  const int rb = by * 128, cb = bx * 128;
  const int tid = threadIdx.x;
  const int l = tid & 63, w = tid >> 6;
  const int wr = w >> 1, wc = w & 1;

  const uint8_t* X = xf8 + (size_t)md * NB * ND;
  fx16 acc[2][2];
  gram128S(X, X, rb, cb, smem, tid, acc);

  // threshold -> 128x128 bit tile in LDS (smem free after gram's final sync)
  uint32_t* tile = (uint32_t*)smem;      // [128][4] words = 2 KiB
  float* Lr = (float*)(smem + 2048);
  float* Lc = (float*)(smem + 2560);
  if (tid < 128) {
    Lr[tid] = lnorm[md * NB + rb + tid];
    Lc[tid] = lnorm[md * NB + cb + tid];
  }
  __syncthreads();

  #pragma unroll
  for (int m = 0; m < 2; ++m)
    #pragma unroll
    for (int r = 0; r < 16; ++r) {
      const int rl0 = wr * 64 + m * 32 + (r & 3) + 8 * (r >> 2);  // + 4*(l>>5)
      const float Lrv = Lr[rl0 + 4 * (l >> 5)];
      #pragma unroll
      for (int n = 0; n < 2; ++n) {
        const int cl = wc * 64 + n * 32 + (l & 31);
        const float cv = acc[m][n][r] / fmaxf(Lrv * Lc[cl], CEPS);
        const uint64_t b = __ballot(cv <= CTHR);
        if (l == 0)  tile[(rl0 + 0) * 4 + wc * 2 + n] = (uint32_t)b;
        if (l == 32) tile[(rl0 + 4) * 4 + wc * 2 + n] = (uint32_t)(b >> 32);
      }
    }
  __syncthreads();

  // direct region: rows [rb,+128) x words [cb/32,+4) — exclusively owned
  for (int t = tid; t < 512; t += 256) {
    const int row = t >> 2, wd = t & 3;
    maskw[((size_t)md * NB + rb + row) * 128 + (cb >> 5) + wd] = tile[t];
  }
  // transposed region: rows [cb,+128) x words [rb/32,+4)
  if (by != bx) {
    for (int t = tid; t < 512; t += 256) {
      const int crow = t & 127;
      const int wp = t >> 7;
      uint32_t wv = 0;
      #pragma unroll
      for (int r = 0; r < 32; ++r) {
        const uint32_t bit = (tile[(wp * 32 + r) * 4 + (crow >> 5)] >> (crow & 31)) & 1u;
        wv |= bit << r;
      }
      maskw[((size_t)md * NB + cb + crow) * 128 + (rb >> 5) + wp] = wv;
    }
  }
}

// ---------- kernel 3: per-pair cross gram + masked exp + count row-partials ----------
// 1D grid 3072 = 8 x 384 with XCD swizzle: each XCD gets a contiguous block
// range = one pair's contiguous row-band -> Xi band (1.5MB) + Xj (4MB) ~ its L2.

__global__ __launch_bounds__(256, 3) void cmc_pair(
    const uint8_t* __restrict__ xf8, const float* __restrict__ lnorm,
    const uint32_t* __restrict__ maskw,
    float* __restrict__ sumexp, float* __restrict__ cntrow,
    float* __restrict__ diagv) {
  __shared__ __align__(16) char smem[32768];
  const int o = blockIdx.x;              // 0..3071
  const int bid = (o & 7) * 384 + (o >> 3);   // XCD-contiguous (3072 % 8 == 0)
  const int p = bid >> 10;               // pair: 0->(0,1) 1->(0,2) 2->(1,2)
  const int rem = bid & 1023;
  const int by = rem >> 5, bx = rem & 31;
  const int mi = (p == 2) ? 1 : 0;
  const int mj = (p == 0) ? 1 : 2;
  const int rb = by * 128, cb = bx * 128;
  const int tid = threadIdx.x;
  const int l = tid & 63, w = tid >> 6;
  const int wr = w >> 1, wc = w & 1;

  const uint8_t* Xi = xf8 + (size_t)mi * NB * ND;
  const uint8_t* Xj = xf8 + (size_t)mj * NB * ND;

  fx16 acc[2][2];
  gram128S(Xi, Xj, rb, cb, smem, tid, acc);

  // stage masks + norms into LDS (smem free after gram's final sync)
  uint32_t* Mt = (uint32_t*)smem;        // Mi [128][4] then Mj [128][4]
  float* Lri = (float*)(smem + 4096);
  float* Lcj = (float*)(smem + 4608);
  for (int t = tid; t < 512; t += 256) {
    const int row = t >> 2, wd = t & 3;
    Mt[t]       = maskw[((size_t)mi * NB + rb + row) * 128 + (cb >> 5) + wd];
    Mt[512 + t] = maskw[((size_t)mj * NB + rb + row) * 128 + (cb >> 5) + wd];
  }
  if (tid < 128) {
    Lri[tid] = lnorm[mi * NB + rb + tid];
    Lcj[tid] = lnorm[mj * NB + cb + tid];
  }
  __syncthreads();

  #pragma unroll
  for (int m = 0; m < 2; ++m)
    #pragma unroll
    for (int r = 0; r < 16; ++r) {
      const int rl = wr * 64 + m * 32 + (r & 3) + 8 * (r >> 2) + 4 * (l >> 5);
      const int rg = rb + rl;
      const float Lrv = Lri[rl];
      float se = 0.f, ct = 0.f;
      #pragma unroll
      for (int n = 0; n < 2; ++n) {
        const int cl = wc * 64 + n * 32 + (l & 31);
        const int cg = cb + cl;
        const uint32_t bi = (Mt[rl * 4 + (cl >> 5)] >> (cl & 31)) & 1u;
        const uint32_t bj = (Mt[512 + rl * 4 + (cl >> 5)] >> (cl & 31)) & 1u;
        const bool msk = bi | bj | (rg == cg);
        const float logit = acc[m][n][r] / fmaxf(Lrv * Lcj[cl], CEPS) * 10.0f;
        if (rg == cg) diagv[p * NB + rg] = logit;
        if (msk) { se += __expf(logit); ct += 1.f; }
      }
      #pragma unroll
      for (int d = 1; d < 32; d <<= 1) {
        se += __shfl_xor(se, d);
        ct += __shfl_xor(ct, d);
      }
      if ((l & 31) == 0) {
        atomicAdd(&sumexp[p * NB + rg], se);
        atomicAdd(&cntrow[p * NB + rg], ct);
      }
    }
}

// ---------- kernel 4: finalize ----------

__global__ __launch_bounds__(256) void cmc_final(
    const float* __restrict__ sumexp, const float* __restrict__ cntrow,
    const float* __restrict__ diagv, float* __restrict__ out) {
  const int tid = threadIdx.x;
  __shared__ float sred[8];
  float lsum = 0.f;
  for (int p = 0; p < 3; ++p) {
    float t = 0.f, c = 0.f;
    for (int r = tid; r < NB; r += 256) {
      const float cnt = cntrow[p * NB + r];
      if (cnt > 1.0f) {
        t += logf(sumexp[p * NB + r]) - diagv[p * NB + r];
        c += 1.f;
      }
    }
    #pragma unroll
    for (int d = 1; d < 64; d <<= 1) { t += __shfl_xor(t, d); c += __shfl_xor(c, d); }
    if ((tid & 63) == 0) { sred[(tid >> 6) * 2] = t; sred[(tid >> 6) * 2 + 1] = c; }
    __syncthreads();
    if (tid == 0) {
      const float tt = sred[0] + sred[2] + sred[4] + sred[6];
      const float cc = sred[1] + sred[3] + sred[5] + sred[7];
      lsum += (cc > 0.f) ? tt / fmaxf(cc, 1.f) : 0.f;
    }
    __syncthreads();
  }
  if (tid == 0) out[0] = lsum / 3.0f;
}

// ---------- launch ----------

extern "C" void kernel_launch(void* const* d_in, const int* in_sizes, int n_in,
                              void* d_out, int out_size, void* d_ws, size_t ws_size,
                              hipStream_t stream) {
  const float* in = (const float*)d_in[0];
  float* out = (float*)d_out;
  char* ws = (char*)d_ws;

  const size_t X8_BYTES = (size_t)3 * NB * ND;          // 12,582,912
  uint8_t* xf8  = (uint8_t*)ws;
  float* lnorm  = (float*)(ws + X8_BYTES);
  float* sumexp = lnorm + 3 * NB;
  float* cntrow = sumexp + 3 * NB;
  float* diagv  = cntrow + 3 * NB;
  uint32_t* maskw = (uint32_t*)(diagv + 3 * NB);        // [3][4096][128] = 6 MB

  // zero both atomically-accumulated buffers (sumexp ++ cntrow contiguous)
  hipMemsetAsync(sumexp, 0, (size_t)2 * 3 * NB * sizeof(float), stream);

  cmc_convert<<<3 * NB, 256, 0, stream>>>(in, xf8, lnorm);
  cmc_selfmask<<<1584, 256, 0, stream>>>(xf8, lnorm, maskw);
  cmc_pair<<<3072, 256, 0, stream>>>(xf8, lnorm, maskw, sumexp, cntrow, diagv);
  cmc_final<<<1, 256, 0, stream>>>(sumexp, cntrow, diagv, out);
}